// Round 3
// baseline (319.695 us; speedup 1.0000x reference)
//
#include <hip/hip_runtime.h>
#include <hip/hip_fp16.h>
#include <hip/hip_cooperative_groups.h>

namespace cg = cooperative_groups;

#define N_ITEMS 100000
#define HID 128
#define NNZ_T 1600000
#define GEMM_TILES 1563            // ceil(100000/64)
#define MAX_BLOCKS 1024            // 4 blocks/CU target (LDS 32KB, VGPR<=128)

typedef unsigned short ushort_t;
typedef unsigned int uint_t;
typedef short bf16x8 __attribute__((ext_vector_type(8)));
typedef float f32x4 __attribute__((ext_vector_type(4)));

static __device__ __forceinline__ ushort_t f32_to_bf16(float f) {
    uint_t u = __float_as_uint(f);
    uint_t r = (u + 0x7FFFu + ((u >> 16) & 1u)) >> 16;   // RNE
    return (ushort_t)r;
}

// One cooperative kernel:
//  A0: row_ptr[r] = lower_bound(rows, r)        (first ~391 blocks, <=1/thread)
//  A1: stage W f32->bf16 into LDS, XOR-swizzled (once per block, amortized
//      over ~1.5 GEMM tiles vs once per tile before)
//  A2: S = fp16(X @ W^T + bias) via 16x16x32 bf16 MFMA, 64-row tiles
//  -- grid.sync() --
//  B : out = A @ S — EXACT round-0 spmm structure (best measured: 61us),
//      grid-strided over row pairs. fp16 hfma2 accum -> identical numerics.
__global__ __launch_bounds__(256, 4) void gcn_fused(
    const float* __restrict__ X, const int* __restrict__ rows,
    const int* __restrict__ cols, const float* __restrict__ vals,
    const float* __restrict__ W, const float* __restrict__ bias,
    ushort_t* __restrict__ S, int* __restrict__ row_ptr,
    float* __restrict__ out, int nblocks) {

    const int tid = threadIdx.x;
    const int lane = tid & 63;
    const int wave = tid >> 6;

    // ---- A0: binary searches (concentrated in low blocks; others skip) ----
    for (int r = blockIdx.x * 256 + tid; r <= N_ITEMS; r += nblocks * 256) {
        int lo = 0, hi = NNZ_T;
        while (lo < hi) {                    // lower_bound(rows, r), rows sorted
            int mid = (lo + hi) >> 1;
            if (rows[mid] < r) lo = mid + 1; else hi = mid;
        }
        row_ptr[r] = lo;
    }

    // ---- A1: stage W into LDS (swizzle: phys = logical ^ ((row&7)<<3)) ----
    __shared__ ushort_t Wl[HID * HID];       // 32 KB bf16
    {
        const float4* Wf = (const float4*)W;
#pragma unroll
        for (int j = 0; j < 8; ++j) {
            const int gblk = j * 256 + tid;  // 16B granule id, 0..2047
            float4 w0 = Wf[gblk * 2];
            float4 w1 = Wf[gblk * 2 + 1];
            bf16x8 v;
            v[0] = (short)f32_to_bf16(w0.x); v[1] = (short)f32_to_bf16(w0.y);
            v[2] = (short)f32_to_bf16(w0.z); v[3] = (short)f32_to_bf16(w0.w);
            v[4] = (short)f32_to_bf16(w1.x); v[5] = (short)f32_to_bf16(w1.y);
            v[6] = (short)f32_to_bf16(w1.z); v[7] = (short)f32_to_bf16(w1.w);
            const int ps = (gblk * 8) ^ (((gblk >> 4) & 7) << 3);
            *(bf16x8*)&Wl[ps] = v;
        }
    }
    __syncthreads();

    // ---- A2: GEMM tiles, grid-stride ----
    const int m = lane & 15;
    const int q = lane >> 4;
    const int swz = (m & 7) << 3;            // row&7 == m&7 for row = nt*16+m
    for (int tile = blockIdx.x; tile < GEMM_TILES; tile += nblocks) {
        const int row0 = tile * 64 + wave * 16;
        int arow = row0 + m;
        if (arow >= N_ITEMS) arow = N_ITEMS - 1;   // clamp (stores guarded)

        f32x4 acc[8] = {};
#pragma unroll
        for (int kb = 0; kb < 4; ++kb) {
            const int k0 = kb * 32 + q * 8;
            float4 a0 = *(const float4*)&X[(size_t)arow * HID + k0];
            float4 a1 = *(const float4*)&X[(size_t)arow * HID + k0 + 4];
            bf16x8 xf;
            xf[0] = (short)f32_to_bf16(a0.x); xf[1] = (short)f32_to_bf16(a0.y);
            xf[2] = (short)f32_to_bf16(a0.z); xf[3] = (short)f32_to_bf16(a0.w);
            xf[4] = (short)f32_to_bf16(a1.x); xf[5] = (short)f32_to_bf16(a1.y);
            xf[6] = (short)f32_to_bf16(a1.z); xf[7] = (short)f32_to_bf16(a1.w);
#pragma unroll
            for (int nt = 0; nt < 8; ++nt) {
                const bf16x8 wf = *(const bf16x8*)&Wl[((nt * 16 + m) * HID + k0) ^ swz];
                acc[nt] = __builtin_amdgcn_mfma_f32_16x16x32_bf16(wf, xf, acc[nt], 0, 0, 0);
            }
        }

        const int srow = row0 + m;
        const bool ok = srow < N_ITEMS;
#pragma unroll
        for (int nt = 0; nt < 8; ++nt) {
            const int c0 = nt * 16 + q * 4;  // 4 consecutive out cols
            float4 bv = *(const float4*)&bias[c0];
            ushort_t h0 = __half_as_ushort(__float2half(acc[nt][0] + bv.x));
            ushort_t h1 = __half_as_ushort(__float2half(acc[nt][1] + bv.y));
            ushort_t h2 = __half_as_ushort(__float2half(acc[nt][2] + bv.z));
            ushort_t h3 = __half_as_ushort(__float2half(acc[nt][3] + bv.w));
            uint2 pk;
            pk.x = (uint_t)h0 | ((uint_t)h1 << 16);
            pk.y = (uint_t)h2 | ((uint_t)h3 << 16);
            if (ok) *(uint2*)&S[(size_t)srow * HID + c0] = pk;
        }
    }

    cg::this_grid().sync();

    // ---- B: spmm — round-0 structure, grid-strided over row pairs ----
    const int g = lane >> 4;                 // edge slot within a quad (0..3)
    const int l = lane & 15;                 // column octet: cols 8*l .. 8*l+7
    const int sel = lane >> 5;               // 0: window A, 1: window B
    const int nwaves = nblocks * 4;

    for (int wid = blockIdx.x * 4 + wave; wid < N_ITEMS / 2; wid += nwaves) {
        const int r0 = wid * 2;              // rows r0, r0+1
        const int2 p01 = *(const int2*)&row_ptr[r0];   // r0 even -> 8B aligned
        const int pEb = row_ptr[r0 + 2];
        int pa = p01.x; const int pEa = p01.y;
        int pb = p01.y;

        __half2 accA[4], accB[4];
#pragma unroll
        for (int j = 0; j < 4; ++j) { accA[j] = __float2half2_rn(0.f); accB[j] = __float2half2_rn(0.f); }

        while (pa < pEa || pb < pEb) {
            // one coalesced load pair fills both rows' 16-slot windows
            const int base = sel ? pb : pa;
            const int end  = sel ? pEb : pEa;
            const int idx  = base + (lane & 15);
            const int cidx = max(min(idx, end - 1), 0);   // clamp (empty-row safe)
            const int c_l  = cols[cidx];
            const float v_l = (idx < end) ? vals[cidx] : 0.f;

            uint4 uA[4], uB[4];
            float vA[4], vB[4];
#pragma unroll
            for (int t = 0; t < 4; ++t) {    // 8 quad-gathers in flight
                const int sa = 4 * t + g;
                const int ca = __shfl(c_l, sa, 64);
                vA[t] = __shfl(v_l, sa, 64);
                uA[t] = *(const uint4*)&S[(size_t)ca * HID + 8 * l];
                const int cb = __shfl(c_l, 32 + sa, 64);
                vB[t] = __shfl(v_l, 32 + sa, 64);
                uB[t] = *(const uint4*)&S[(size_t)cb * HID + 8 * l];
            }
#pragma unroll
            for (int t = 0; t < 4; ++t) {
                const __half2 wa = __float2half2_rn(vA[t]);
                accA[0] = __hfma2(wa, *(const __half2*)&uA[t].x, accA[0]);
                accA[1] = __hfma2(wa, *(const __half2*)&uA[t].y, accA[1]);
                accA[2] = __hfma2(wa, *(const __half2*)&uA[t].z, accA[2]);
                accA[3] = __hfma2(wa, *(const __half2*)&uA[t].w, accA[3]);
                const __half2 wb = __float2half2_rn(vB[t]);
                accB[0] = __hfma2(wb, *(const __half2*)&uB[t].x, accB[0]);
                accB[1] = __hfma2(wb, *(const __half2*)&uB[t].y, accB[1]);
                accB[2] = __hfma2(wb, *(const __half2*)&uB[t].z, accB[2]);
                accB[3] = __hfma2(wb, *(const __half2*)&uB[t].w, accB[3]);
            }
            pa = min(pa + 16, pEa);
            pb = min(pb + 16, pEb);
        }

        // unpack to f32; xor-reduce over the 4 edge-groups
        float fA[8], fB[8];
#pragma unroll
        for (int j = 0; j < 4; ++j) {
            fA[2 * j] = __low2float(accA[j]);  fA[2 * j + 1] = __high2float(accA[j]);
            fB[2 * j] = __low2float(accB[j]);  fB[2 * j + 1] = __high2float(accB[j]);
        }
#pragma unroll
        for (int e = 0; e < 8; ++e) {
            fA[e] += __shfl_xor(fA[e], 16, 64);
            fA[e] += __shfl_xor(fA[e], 32, 64);
            fB[e] += __shfl_xor(fB[e], 16, 64);
            fB[e] += __shfl_xor(fB[e], 32, 64);
        }
        if (g == 0) {                        // lanes 0-15: row A
            float* p = &out[(size_t)r0 * HID + 8 * l];
            *(float4*)p       = make_float4(fA[0], fA[1], fA[2], fA[3]);
            *(float4*)(p + 4) = make_float4(fA[4], fA[5], fA[6], fA[7]);
        } else if (g == 1 && r0 + 1 < N_ITEMS) {  // lanes 16-31: row B
            float* p = &out[(size_t)(r0 + 1) * HID + 8 * l];
            *(float4*)p       = make_float4(fB[0], fB[1], fB[2], fB[3]);
            *(float4*)(p + 4) = make_float4(fB[4], fB[5], fB[6], fB[7]);
        }
    }
}

extern "C" void kernel_launch(void* const* d_in, const int* in_sizes, int n_in,
                              void* d_out, int out_size, void* d_ws, size_t ws_size,
                              hipStream_t stream) {
    const float* X    = (const float*)d_in[0];
    const int*   rows = (const int*)  d_in[1];
    const int*   cols = (const int*)  d_in[2];
    const float* vals = (const float*)d_in[3];
    const float* W    = (const float*)d_in[4];
    const float* bias = (const float*)d_in[5];
    float* out = (float*)d_out;

    ushort_t* S       = (ushort_t*)d_ws;                    // 25.6 MB (fp16)
    int*      row_ptr = (int*)(S + (size_t)N_ITEMS * HID);  // 400 KB

    // co-residency-safe grid size (cached; host-only queries, capture-safe)
    static int nblocks = 0;
    if (nblocks == 0) {
        int per_cu = 0;
        hipOccupancyMaxActiveBlocksPerMultiprocessor(
            &per_cu, reinterpret_cast<const void*>(gcn_fused), 256, 0);
        int num_cu = 256;
        hipDeviceProp_t prop;
        if (hipGetDeviceProperties(&prop, 0) == hipSuccess && prop.multiProcessorCount > 0)
            num_cu = prop.multiProcessorCount;
        nblocks = (per_cu > 0 ? per_cu : 1) * num_cu;
        if (nblocks > MAX_BLOCKS) nblocks = MAX_BLOCKS;
        if (nblocks < 256) nblocks = 256;
    }

    void* args[] = {(void*)&X, (void*)&rows, (void*)&cols, (void*)&vals,
                    (void*)&W, (void*)&bias, (void*)&S, (void*)&row_ptr,
                    (void*)&out, (void*)&nblocks};
    hipLaunchCooperativeKernel(reinterpret_cast<void*>(gcn_fused),
                               dim3(nblocks), dim3(256), args, 0, stream);
}

// Round 4
// 208.078 us; speedup vs baseline: 1.5364x; 1.5364x over previous
//
#include <hip/hip_runtime.h>
#include <hip/hip_fp16.h>

#define N_ITEMS 100000
#define HID 128
#define NNZ_T 1600000
#define RP_BLOCKS 391              // ceil(100001/256) binary-search blocks (FIRST)
#define GEMM_TILES 1563            // ceil(100000/64)
#define GEMM_BLOCKS 781            // 2 tiles per block: W staged once per 2 tiles
#define SPMM_BLOCKS 12500          // round-0 proven config: 1 row-pair per wave

typedef unsigned short ushort_t;
typedef unsigned int uint_t;
typedef short bf16x8 __attribute__((ext_vector_type(8)));
typedef float f32x4 __attribute__((ext_vector_type(4)));
typedef float f32x4v __attribute__((ext_vector_type(4)));
typedef uint_t u32x4v __attribute__((ext_vector_type(4)));

static __device__ __forceinline__ ushort_t f32_to_bf16(float f) {
    uint_t u = __float_as_uint(f);
    uint_t r = (u + 0x7FFFu + ((u >> 16) & 1u)) >> 16;   // RNE
    return (ushort_t)r;
}

static __device__ __forceinline__ __half2 u2h2(uint_t w) {
    union { uint_t u; __half2 h; } c; c.u = w; return c.h;
}

// === K1: blocks [0,RP_BLOCKS) build row_ptr; the rest grid-stride GEMM tiles,
// staging W f32->bf16 into LDS ONCE per block (amortized over 2 tiles).
// X loads nontemporal (streamed once; don't pollute L1/L2).
__global__ __launch_bounds__(256) void prep_gemm(
    const float* __restrict__ X, const float* __restrict__ W,
    const float* __restrict__ bias, const int* __restrict__ rows,
    ushort_t* __restrict__ S, int* __restrict__ row_ptr) {
    if (blockIdx.x < RP_BLOCKS) {
        int r = blockIdx.x * 256 + threadIdx.x;
        if (r > N_ITEMS) return;
        int lo = 0, hi = NNZ_T;
        while (lo < hi) {                       // lower_bound(rows, r), rows sorted
            int mid = (lo + hi) >> 1;
            if (rows[mid] < r) lo = mid + 1; else hi = mid;
        }
        row_ptr[r] = lo;
        return;
    }

    __shared__ ushort_t Wl[HID * HID];          // 32 KB bf16, XOR-swizzled
    {
        const int t = threadIdx.x;
        const float4* Wf = (const float4*)W;
#pragma unroll
        for (int j = 0; j < 8; ++j) {
            const int gblk = j * 256 + t;       // 16B granule id, 0..2047
            float4 w0 = Wf[gblk * 2];
            float4 w1 = Wf[gblk * 2 + 1];
            bf16x8 v;
            v[0] = (short)f32_to_bf16(w0.x); v[1] = (short)f32_to_bf16(w0.y);
            v[2] = (short)f32_to_bf16(w0.z); v[3] = (short)f32_to_bf16(w0.w);
            v[4] = (short)f32_to_bf16(w1.x); v[5] = (short)f32_to_bf16(w1.y);
            v[6] = (short)f32_to_bf16(w1.z); v[7] = (short)f32_to_bf16(w1.w);
            const int ps = (gblk * 8) ^ (((gblk >> 4) & 7) << 3);  // phys short idx
            *(bf16x8*)&Wl[ps] = v;
        }
    }
    __syncthreads();

    const int lane = threadIdx.x & 63;
    const int wave = threadIdx.x >> 6;
    const int m = lane & 15;
    const int q = lane >> 4;
    const int swz = (m & 7) << 3;               // row&7 == m&7 for row = nt*16+m

    for (int tile = blockIdx.x - RP_BLOCKS; tile < GEMM_TILES; tile += GEMM_BLOCKS) {
        const int row0 = tile * 64 + wave * 16;
        int arow = row0 + m;
        if (arow >= N_ITEMS) arow = N_ITEMS - 1;   // clamp (stores guarded)

        f32x4 acc[8] = {};
#pragma unroll
        for (int kb = 0; kb < 4; ++kb) {
            const int k0 = kb * 32 + q * 8;
            f32x4v a0 = __builtin_nontemporal_load((const f32x4v*)&X[(size_t)arow * HID + k0]);
            f32x4v a1 = __builtin_nontemporal_load((const f32x4v*)&X[(size_t)arow * HID + k0 + 4]);
            bf16x8 xf;
            xf[0] = (short)f32_to_bf16(a0[0]); xf[1] = (short)f32_to_bf16(a0[1]);
            xf[2] = (short)f32_to_bf16(a0[2]); xf[3] = (short)f32_to_bf16(a0[3]);
            xf[4] = (short)f32_to_bf16(a1[0]); xf[5] = (short)f32_to_bf16(a1[1]);
            xf[6] = (short)f32_to_bf16(a1[2]); xf[7] = (short)f32_to_bf16(a1[3]);
#pragma unroll
            for (int nt = 0; nt < 8; ++nt) {
                const bf16x8 wf = *(const bf16x8*)&Wl[((nt * 16 + m) * HID + k0) ^ swz];
                acc[nt] = __builtin_amdgcn_mfma_f32_16x16x32_bf16(wf, xf, acc[nt], 0, 0, 0);
            }
        }

        const int srow = row0 + m;
        const bool ok = srow < N_ITEMS;
#pragma unroll
        for (int nt = 0; nt < 8; ++nt) {
            const int c0 = nt * 16 + q * 4;     // 4 consecutive out cols
            float4 bv = *(const float4*)&bias[c0];
            ushort_t h0 = __half_as_ushort(__float2half(acc[nt][0] + bv.x));
            ushort_t h1 = __half_as_ushort(__float2half(acc[nt][1] + bv.y));
            ushort_t h2 = __half_as_ushort(__float2half(acc[nt][2] + bv.z));
            ushort_t h3 = __half_as_ushort(__float2half(acc[nt][3] + bv.w));
            uint2 pk;
            pk.x = (uint_t)h0 | ((uint_t)h1 << 16);
            pk.y = (uint_t)h2 | ((uint_t)h3 << 16);
            if (ok) *(uint2*)&S[(size_t)srow * HID + c0] = pk;
        }
    }
}

// === K2: out[row] = sum vals*S[cols] — EXACT round-0 structure (measured 61us)
// with two pure cache-policy changes:
//   - S gathers via __builtin_nontemporal_load: random 25.6MB set never L1-hits,
//     so L1 allocation is pure fill-rate overhead (theory: L1-fill is the wall)
//   - out stores nontemporal: never re-read; don't evict S lines from L2
__global__ __launch_bounds__(256) void spmm_csr(
    const int* __restrict__ cols, const float* __restrict__ vals,
    const int* __restrict__ row_ptr, const ushort_t* __restrict__ S,
    float* __restrict__ out) {
    const int lane = threadIdx.x & 63;
    const int wid = blockIdx.x * 4 + ((threadIdx.x >> 6) & 3);
    const int r0 = wid * 2;                 // rows r0, r0+1
    if (r0 >= N_ITEMS) return;

    const int g = lane >> 4;                // edge slot within a quad (0..3)
    const int l = lane & 15;                // column octet: cols 8*l .. 8*l+7
    const int sel = lane >> 5;              // 0: window A, 1: window B

    const int2 p01 = *(const int2*)&row_ptr[r0];      // r0 even -> 8B aligned
    const int pEb = row_ptr[r0 + 2];                  // r0+2 <= N_ITEMS: valid
    int pa = p01.x; const int pEa = p01.y;
    int pb = p01.y;

    __half2 accA[4], accB[4];
#pragma unroll
    for (int j = 0; j < 4; ++j) { accA[j] = __float2half2_rn(0.f); accB[j] = __float2half2_rn(0.f); }

    while (pa < pEa || pb < pEb) {
        // one coalesced load pair fills both rows' windows
        const int base = sel ? pb : pa;
        const int end  = sel ? pEb : pEa;
        const int idx  = base + (lane & 15);
        const int cidx = max(min(idx, end - 1), 0);   // clamp (empty-row safe)
        const int c_l  = cols[cidx];
        const float v_l = (idx < end) ? vals[cidx] : 0.f;

        u32x4v uA[4], uB[4];
        float vA[4], vB[4];
#pragma unroll
        for (int t = 0; t < 4; ++t) {                 // 8 quad-gathers in flight
            const int sa = 4 * t + g;
            const int ca = __shfl(c_l, sa, 64);
            vA[t] = __shfl(v_l, sa, 64);
            uA[t] = __builtin_nontemporal_load((const u32x4v*)&S[(size_t)ca * HID + 8 * l]);
            const int cb = __shfl(c_l, 32 + sa, 64);  // window B (lane 32-47)
            vB[t] = __shfl(v_l, 32 + sa, 64);
            uB[t] = __builtin_nontemporal_load((const u32x4v*)&S[(size_t)cb * HID + 8 * l]);
        }
#pragma unroll
        for (int t = 0; t < 4; ++t) {
            const __half2 wa = __float2half2_rn(vA[t]);
            accA[0] = __hfma2(wa, u2h2(uA[t][0]), accA[0]);
            accA[1] = __hfma2(wa, u2h2(uA[t][1]), accA[1]);
            accA[2] = __hfma2(wa, u2h2(uA[t][2]), accA[2]);
            accA[3] = __hfma2(wa, u2h2(uA[t][3]), accA[3]);
            const __half2 wb = __float2half2_rn(vB[t]);
            accB[0] = __hfma2(wb, u2h2(uB[t][0]), accB[0]);
            accB[1] = __hfma2(wb, u2h2(uB[t][1]), accB[1]);
            accB[2] = __hfma2(wb, u2h2(uB[t][2]), accB[2]);
            accB[3] = __hfma2(wb, u2h2(uB[t][3]), accB[3]);
        }
        pa = min(pa + 16, pEa);
        pb = min(pb + 16, pEb);
    }

    // unpack to f32; xor-reduce over the 4 edge-groups (lanes l,l+16,l+32,l+48)
    float fA[8], fB[8];
#pragma unroll
    for (int j = 0; j < 4; ++j) {
        fA[2 * j] = __low2float(accA[j]);  fA[2 * j + 1] = __high2float(accA[j]);
        fB[2 * j] = __low2float(accB[j]);  fB[2 * j + 1] = __high2float(accB[j]);
    }
#pragma unroll
    for (int e = 0; e < 8; ++e) {
        fA[e] += __shfl_xor(fA[e], 16, 64);
        fA[e] += __shfl_xor(fA[e], 32, 64);
        fB[e] += __shfl_xor(fB[e], 16, 64);
        fB[e] += __shfl_xor(fB[e], 32, 64);
    }
    if (g == 0) {                                     // lanes 0-15: row A
        float* p = &out[(size_t)r0 * HID + 8 * l];
        f32x4v o0; o0[0] = fA[0]; o0[1] = fA[1]; o0[2] = fA[2]; o0[3] = fA[3];
        f32x4v o1; o1[0] = fA[4]; o1[1] = fA[5]; o1[2] = fA[6]; o1[3] = fA[7];
        __builtin_nontemporal_store(o0, (f32x4v*)p);
        __builtin_nontemporal_store(o1, (f32x4v*)(p + 4));
    } else if (g == 1 && r0 + 1 < N_ITEMS) {          // lanes 16-31: row B
        float* p = &out[(size_t)(r0 + 1) * HID + 8 * l];
        f32x4v o0; o0[0] = fB[0]; o0[1] = fB[1]; o0[2] = fB[2]; o0[3] = fB[3];
        f32x4v o1; o1[0] = fB[4]; o1[1] = fB[5]; o1[2] = fB[6]; o1[3] = fB[7];
        __builtin_nontemporal_store(o0, (f32x4v*)p);
        __builtin_nontemporal_store(o1, (f32x4v*)(p + 4));
    }
}

extern "C" void kernel_launch(void* const* d_in, const int* in_sizes, int n_in,
                              void* d_out, int out_size, void* d_ws, size_t ws_size,
                              hipStream_t stream) {
    const float* X    = (const float*)d_in[0];
    const int*   rows = (const int*)  d_in[1];
    const int*   cols = (const int*)  d_in[2];
    const float* vals = (const float*)d_in[3];
    const float* W    = (const float*)d_in[4];
    const float* bias = (const float*)d_in[5];
    float* out = (float*)d_out;

    ushort_t* S       = (ushort_t*)d_ws;                    // 25.6 MB (fp16)
    int*      row_ptr = (int*)(S + (size_t)N_ITEMS * HID);  // 400 KB

    prep_gemm<<<RP_BLOCKS + GEMM_BLOCKS, 256, 0, stream>>>(X, W, bias, rows, S, row_ptr);
    spmm_csr<<<SPMM_BLOCKS, 256, 0, stream>>>(cols, vals, row_ptr, S, out);
}

// Round 5
// 187.302 us; speedup vs baseline: 1.7068x; 1.1109x over previous
//
#include <hip/hip_runtime.h>
#include <hip/hip_fp16.h>

#define N_ITEMS 100000
#define HID 128
#define NNZ_T 1600000
#define GEMM_TILES 1563            // ceil(100000/64)
#define GEMM_BLOCKS 781            // 2 tiles per block: W staged once per 2 tiles
#define RP_BLOCKS 391              // binary-search blocks, placed LAST (backfill)
#define SPMM_BLOCKS 25000          // 1 row per wave, 4 waves/block

typedef unsigned short ushort_t;
typedef unsigned int uint_t;
typedef short bf16x8 __attribute__((ext_vector_type(8)));
typedef float f32x4 __attribute__((ext_vector_type(4)));

static __device__ __forceinline__ ushort_t f32_to_bf16(float f) {
    uint_t u = __float_as_uint(f);
    uint_t r = (u + 0x7FFFu + ((u >> 16) & 1u)) >> 16;   // RNE
    return (ushort_t)r;
}

// === K1: blocks [0,GEMM_BLOCKS) grid-stride the GEMM tiles (W staged in LDS
// once per block, XOR-swizzled); blocks [GEMM_BLOCKS..+RP_BLOCKS) do the
// row_ptr binary searches — placed LAST so they backfill the GEMM tail
// instead of delaying GEMM dispatch. Plain (cached) loads everywhere: round 4
// showed nontemporal costs ~6us here and +18us in spmm.
__global__ __launch_bounds__(256) void prep_gemm(
    const float* __restrict__ X, const float* __restrict__ W,
    const float* __restrict__ bias, const int* __restrict__ rows,
    ushort_t* __restrict__ S, int* __restrict__ row_ptr) {
    if (blockIdx.x >= GEMM_BLOCKS) {
        int r = (blockIdx.x - GEMM_BLOCKS) * 256 + threadIdx.x;
        if (r > N_ITEMS) return;
        int lo = 0, hi = NNZ_T;
        while (lo < hi) {                       // lower_bound(rows, r), rows sorted
            int mid = (lo + hi) >> 1;
            if (rows[mid] < r) lo = mid + 1; else hi = mid;
        }
        row_ptr[r] = lo;
        return;
    }

    __shared__ ushort_t Wl[HID * HID];          // 32 KB bf16, XOR-swizzled
    {
        const int t = threadIdx.x;
        const float4* Wf = (const float4*)W;
#pragma unroll
        for (int j = 0; j < 8; ++j) {
            const int gblk = j * 256 + t;       // 16B granule id, 0..2047
            float4 w0 = Wf[gblk * 2];
            float4 w1 = Wf[gblk * 2 + 1];
            bf16x8 v;
            v[0] = (short)f32_to_bf16(w0.x); v[1] = (short)f32_to_bf16(w0.y);
            v[2] = (short)f32_to_bf16(w0.z); v[3] = (short)f32_to_bf16(w0.w);
            v[4] = (short)f32_to_bf16(w1.x); v[5] = (short)f32_to_bf16(w1.y);
            v[6] = (short)f32_to_bf16(w1.z); v[7] = (short)f32_to_bf16(w1.w);
            const int ps = (gblk * 8) ^ (((gblk >> 4) & 7) << 3);  // phys short idx
            *(bf16x8*)&Wl[ps] = v;
        }
    }
    __syncthreads();

    const int lane = threadIdx.x & 63;
    const int wave = threadIdx.x >> 6;
    const int m = lane & 15;
    const int q = lane >> 4;
    const int swz = (m & 7) << 3;               // row&7 == m&7 for row = nt*16+m

    for (int tile = blockIdx.x; tile < GEMM_TILES; tile += GEMM_BLOCKS) {
        const int row0 = tile * 64 + wave * 16;
        int arow = row0 + m;
        if (arow >= N_ITEMS) arow = N_ITEMS - 1;   // clamp (stores guarded)

        f32x4 acc[8] = {};
#pragma unroll
        for (int kb = 0; kb < 4; ++kb) {
            const int k0 = kb * 32 + q * 8;
            float4 a0 = *(const float4*)&X[(size_t)arow * HID + k0];
            float4 a1 = *(const float4*)&X[(size_t)arow * HID + k0 + 4];
            bf16x8 xf;
            xf[0] = (short)f32_to_bf16(a0.x); xf[1] = (short)f32_to_bf16(a0.y);
            xf[2] = (short)f32_to_bf16(a0.z); xf[3] = (short)f32_to_bf16(a0.w);
            xf[4] = (short)f32_to_bf16(a1.x); xf[5] = (short)f32_to_bf16(a1.y);
            xf[6] = (short)f32_to_bf16(a1.z); xf[7] = (short)f32_to_bf16(a1.w);
#pragma unroll
            for (int nt = 0; nt < 8; ++nt) {
                const bf16x8 wf = *(const bf16x8*)&Wl[((nt * 16 + m) * HID + k0) ^ swz];
                acc[nt] = __builtin_amdgcn_mfma_f32_16x16x32_bf16(wf, xf, acc[nt], 0, 0, 0);
            }
        }

        const int srow = row0 + m;
        const bool ok = srow < N_ITEMS;
#pragma unroll
        for (int nt = 0; nt < 8; ++nt) {
            const int c0 = nt * 16 + q * 4;     // 4 consecutive out cols
            float4 bv = *(const float4*)&bias[c0];
            ushort_t h0 = __half_as_ushort(__float2half(acc[nt][0] + bv.x));
            ushort_t h1 = __half_as_ushort(__float2half(acc[nt][1] + bv.y));
            ushort_t h2 = __half_as_ushort(__float2half(acc[nt][2] + bv.z));
            ushort_t h3 = __half_as_ushort(__float2half(acc[nt][3] + bv.w));
            uint2 pk;
            pk.x = (uint_t)h0 | ((uint_t)h1 << 16);
            pk.y = (uint_t)h2 | ((uint_t)h3 << 16);
            if (ok) *(uint2*)&S[(size_t)srow * HID + c0] = pk;
        }
    }
}

// === K2: out[row] = sum vals*S[cols] — ONE row per wave (de-confounds round 2:
// slot-fetches 2.69M -> 2.16M via less window padding, AND waves 50k -> 100k
// for occupancy). Inner loop identical to round-0's row-A path: 16-slot
// windows, 4 quad-gathers in flight, fp16 hfma accumulate (same summation
// order -> bit-identical numerics). Plain cached loads (r4: nt regressed).
__global__ __launch_bounds__(256) void spmm_csr(
    const int* __restrict__ cols, const float* __restrict__ vals,
    const int* __restrict__ row_ptr, const ushort_t* __restrict__ S,
    float* __restrict__ out) {
    const int lane = threadIdx.x & 63;
    const int r = blockIdx.x * 4 + (threadIdx.x >> 6);    // one row per wave
    if (r >= N_ITEMS) return;

    const int g = lane >> 4;                // edge slot within a quad (0..3)
    const int l = lane & 15;                // column octet: cols 8*l .. 8*l+7

    int pa = row_ptr[r];
    const int pE = row_ptr[r + 1];

    __half2 acc[4];
#pragma unroll
    for (int j = 0; j < 4; ++j) acc[j] = __float2half2_rn(0.f);

    while (pa < pE) {
        // lanes 0-15 load 16 contiguous (col,val); other groups duplicate (1 line)
        const int idx  = pa + l;
        const int cidx = min(idx, pE - 1);            // pE > pa >= 0 here
        const int c_l  = cols[cidx];
        const float v_l = (idx < pE) ? vals[cidx] : 0.f;

        uint4 u[4];
        float vv[4];
#pragma unroll
        for (int t = 0; t < 4; ++t) {                 // 4 quad-gathers in flight
            const int s = 4 * t + g;                  // slot index 0..15
            const int ct = __shfl(c_l, s, 64);
            vv[t] = __shfl(v_l, s, 64);
            u[t] = *(const uint4*)&S[(size_t)ct * HID + 8 * l];
        }
#pragma unroll
        for (int t = 0; t < 4; ++t) {
            const __half2 w = __float2half2_rn(vv[t]);
            acc[0] = __hfma2(w, *(const __half2*)&u[t].x, acc[0]);
            acc[1] = __hfma2(w, *(const __half2*)&u[t].y, acc[1]);
            acc[2] = __hfma2(w, *(const __half2*)&u[t].z, acc[2]);
            acc[3] = __hfma2(w, *(const __half2*)&u[t].w, acc[3]);
        }
        pa += 16;
    }

    // unpack to f32; reduce over the 4 edge-groups (lanes l, l+16, l+32, l+48)
    float f[8];
#pragma unroll
    for (int j = 0; j < 4; ++j) {
        f[2 * j] = __low2float(acc[j]);  f[2 * j + 1] = __high2float(acc[j]);
    }
#pragma unroll
    for (int e = 0; e < 8; ++e) {
        f[e] += __shfl_xor(f[e], 16, 64);
        f[e] += __shfl_xor(f[e], 32, 64);
    }
    if (g == 0) {                           // lanes 0-15 store the 512B row
        float* p = &out[(size_t)r * HID + 8 * l];
        *(float4*)p       = make_float4(f[0], f[1], f[2], f[3]);
        *(float4*)(p + 4) = make_float4(f[4], f[5], f[6], f[7]);
    }
}

extern "C" void kernel_launch(void* const* d_in, const int* in_sizes, int n_in,
                              void* d_out, int out_size, void* d_ws, size_t ws_size,
                              hipStream_t stream) {
    const float* X    = (const float*)d_in[0];
    const int*   rows = (const int*)  d_in[1];
    const int*   cols = (const int*)  d_in[2];
    const float* vals = (const float*)d_in[3];
    const float* W    = (const float*)d_in[4];
    const float* bias = (const float*)d_in[5];
    float* out = (float*)d_out;

    ushort_t* S       = (ushort_t*)d_ws;                    // 25.6 MB (fp16)
    int*      row_ptr = (int*)(S + (size_t)N_ITEMS * HID);  // 400 KB

    prep_gemm<<<GEMM_BLOCKS + RP_BLOCKS, 256, 0, stream>>>(X, W, bias, rows, S, row_ptr);
    spmm_csr<<<SPMM_BLOCKS, 256, 0, stream>>>(cols, vals, row_ptr, S, out);
}